// Round 1
// 192.636 us; speedup vs baseline: 1.3678x; 1.3678x over previous
//
#include <hip/hip_runtime.h>
#include <math.h>

// VectorQuantizer: argmin_k ||x_n - c_k||^2, N=32768, K=8192, D=64, fp32.
// Round-7: 2-plane f16 split (11-bit significand -> 22+ bits over 2 planes),
// 3 MFMA products instead of 6 -> MFMA floor halves (92 -> 47 us).
//
// Numerics: v = h1 + 2^-12*h2' + r,  |r| <= 2^-24|v| (+2^-25 abs for tiny v).
//  * h1 = f16(v), zeroed when |v| < 2^-14 so h1 is never f16-denormal
//    (possible MFMA denorm flush would otherwise cost ~6e-5 per element).
//  * h2' = f16((v - h1) * 2^12): residual scaled into f16-NORMAL range.
//  * cross = h1g1 + 2^-12*(h1g2' + h2'g1); dropped terms ~3*2^-24*Sum|x_d c_d|
//    ~= 2e-5 worst -- same fp32-rounding class as the round-6 bf16 6-product
//    scheme (which passed absmax 0), with HALF the fp32 accumulation adds.
//  * dist / tie semantics bit-identical in structure to round-6:
//    dist = fmaf(-2,acc,xsq)+csq, strict < ascending code, u64 mins.
// Staging: B via global_load_lds width=16 (layout is lane-linear chunks ->
// exact HW pattern, no VGPR round-trip, one barrier per tile). csq read
// directly from global per tile (L2-resident). LDS 75.7 -> 50.4 KB.
// C/D layout (measured m74/m101): col=lane&31, row=(reg&3)+8*(reg>>2)+4*(lane>>5).

typedef __attribute__((ext_vector_type(8)))  _Float16 h8v;
typedef __attribute__((ext_vector_type(16))) float f16v;
typedef __attribute__((ext_vector_type(4)))  float f4v;

constexpr int NROWS = 32768;
constexpr int KC    = 8192;
constexpr int DD    = 64;
constexpr int TPB   = 256;                 // 4 waves
constexpr int BROWS = 64;                  // rows per block (2 stripes x 32)
constexpr int BTILE = 64;                  // codes per tile (2 x 32-code subtiles)
constexpr int NT    = KC / BTILE;          // 128 tiles
constexpr int TILE_HALFS = BTILE * DD * 2; // 8192 halves = 16 KB per tile

__device__ __forceinline__ void split2h(float v, _Float16& h1, _Float16& h2) {
  const float av = fabsf(v);
  _Float16 a = (_Float16)v;                 // RNE
  if (av < 6.1035156e-5f) a = (_Float16)0.f; // keep plane-1 out of f16 denormals
  h1 = a;
  h2 = (_Float16)((v - (float)a) * 4096.f); // exact residual, scaled 2^12
}

__device__ __forceinline__ void gload_lds16(const void* g, void* l) {
  __builtin_amdgcn_global_load_lds(
      (const __attribute__((address_space(1))) void*)g,
      (__attribute__((address_space(3))) void*)l, 16, 0, 0);
}

// Pre-kernel: blocks [0,32): split cb -> frag-ordered bSwz (2 f16 planes) +
// csq (sequential fmaf chain, identical to round-6). blocks [32,160): xsq.
__global__ void vq_pre_kernel(const float* __restrict__ x,
                              const float* __restrict__ cb,
                              _Float16* __restrict__ bSwz,
                              float* __restrict__ csq,
                              float* __restrict__ xsq) {
  const int bid = blockIdx.x, tid = threadIdx.x;
  if (bid < KC / TPB) {
    const int code = bid * TPB + tid;
    const float* cp = cb + (size_t)code * DD;
    float v[DD];
#pragma unroll
    for (int d = 0; d < DD; d += 4) {
      const float4 g = *(const float4*)(cp + d);
      v[d] = g.x; v[d + 1] = g.y; v[d + 2] = g.z; v[d + 3] = g.w;
    }
    float s = 0.f;
#pragma unroll
    for (int d = 0; d < DD; ++d) s = fmaf(v[d], v[d], s);
    csq[code] = s;
    _Float16 p1[DD], p2[DD];
#pragma unroll
    for (int d = 0; d < DD; ++d) split2h(v[d], p1[d], p2[d]);
    // 32-code group g, lane slot l; chunk (p,kc) holds 64 lanes x 8 f16:
    // lane (h*32+l) = code (g*32+l), k = kc*16 + h*8 + j.
    const int g = code >> 5, l = code & 31;
    _Float16* base = bSwz + (size_t)g * 4096;
#pragma unroll
    for (int p = 0; p < 2; ++p) {
      const _Float16* pl = p ? p2 : p1;
#pragma unroll
      for (int kc4 = 0; kc4 < 4; ++kc4)
#pragma unroll
        for (int h = 0; h < 2; ++h) {
          h8v wv;
#pragma unroll
          for (int j = 0; j < 8; ++j) wv[j] = pl[kc4 * 16 + h * 8 + j];
          *(h8v*)(base + (p * 4 + kc4) * 512 + (h * 32 + l) * 8) = wv;
        }
    }
  } else {
    const int n = (bid - KC / TPB) * TPB + tid;
    const float* xp = x + (size_t)n * DD;
    float s = 0.f;
#pragma unroll
    for (int d = 0; d < DD; ++d) s = fmaf(xp[d], xp[d], s);
    xsq[n] = s;
  }
}

__global__ __launch_bounds__(TPB, 2)
void vq_mfma_kernel(const float* __restrict__ x, const _Float16* __restrict__ bSwz,
                    const float* __restrict__ csq_g, const float* __restrict__ xsq_g,
                    int* __restrict__ out) {
  __shared__ alignas(16) _Float16 ldsA[2][BROWS][DD];   // 16384 B
  __shared__ alignas(16) _Float16 ldsB[2][TILE_HALFS];  // 32768 B
  __shared__ alignas(16) float ldsXsq[BROWS];           // 256 B
  __shared__ unsigned long long ldsRed[BROWS][2];       // 1024 B

  const int tid  = threadIdx.x;
  const int lane = tid & 63;
  const int w    = tid >> 6;
  const int s    = w & 1;        // row stripe (32 rows)
  const int ch   = w >> 1;       // code half (32 codes)
  const int half = lane >> 5;
  const int col  = lane & 31;
  const int blockRow = blockIdx.x * BROWS;

  // ---- Stage B tile 0: async global->LDS, lane-linear 16 B chunks.
  {
    const _Float16* src0 = bSwz + (size_t)(w * 4) * 512 + lane * 8;
#pragma unroll
    for (int j = 0; j < 4; ++j)
      gload_lds16(src0 + j * 512, &ldsB[0][(w * 4 + j) * 512]);
  }
  // ---- Stage A: split x rows into 2 f16 planes in LDS (once per block).
  {
    const int row = tid >> 2, dseg = (tid & 3) * 16;
    const float* xp = x + (size_t)(blockRow + row) * DD + dseg;
    float v[16];
#pragma unroll
    for (int d = 0; d < 16; d += 4) {
      const float4 g = *(const float4*)(xp + d);
      v[d] = g.x; v[d + 1] = g.y; v[d + 2] = g.z; v[d + 3] = g.w;
    }
    _Float16 qa[16], qb[16];
#pragma unroll
    for (int e = 0; e < 16; ++e) split2h(v[e], qa[e], qb[e]);
#pragma unroll
    for (int h2 = 0; h2 < 2; ++h2) {
      h8v a, b;
#pragma unroll
      for (int j = 0; j < 8; ++j) { a[j] = qa[h2 * 8 + j]; b[j] = qb[h2 * 8 + j]; }
      *(h8v*)&ldsA[0][row][dseg + h2 * 8] = a;
      *(h8v*)&ldsA[1][row][dseg + h2 * 8] = b;
    }
  }
  if (tid < BROWS) ldsXsq[tid] = xsq_g[blockRow + tid];
  __syncthreads();   // drains vmcnt -> tile 0 resident

  // ---- A fragments resident: 2 planes x 4 kchunks x 8 f16 = 32 VGPR.
  h8v afr[2][4];
#pragma unroll
  for (int p = 0; p < 2; ++p)
#pragma unroll
    for (int kc4 = 0; kc4 < 4; ++kc4)
      afr[p][kc4] = *(const h8v*)&ldsA[p][s * 32 + col][kc4 * 16 + half * 8];

  // xsq for this lane's 16 C-slots: row = s*32 + (i&3) + 8*(i>>2) + 4*half.
  float xq[16];
  {
    const float* xb = &ldsXsq[s * 32 + 4 * half];
#pragma unroll
    for (int g8 = 0; g8 < 4; ++g8) {
      const f4v t4 = *(const f4v*)(xb + g8 * 8);
      xq[g8 * 4] = t4[0]; xq[g8 * 4 + 1] = t4[1];
      xq[g8 * 4 + 2] = t4[2]; xq[g8 * 4 + 3] = t4[3];
    }
  }

  float bestD[16];
  unsigned bestC[16];
#pragma unroll
  for (int i = 0; i < 16; ++i) { bestD[i] = INFINITY; bestC[i] = 0u; }

  for (int t = 0; t < NT; ++t) {
    const int buf = t & 1;
    // Prefetch next tile straight into the other LDS buffer (async; the
    // end-of-tile barrier's vmcnt drain guarantees it lands in time).
    if (t + 1 < NT) {
      const _Float16* src =
          bSwz + (size_t)(t + 1) * TILE_HALFS + (size_t)(w * 4) * 512 + lane * 8;
#pragma unroll
      for (int j = 0; j < 4; ++j)
        gload_lds16(src + j * 512, &ldsB[buf ^ 1][(w * 4 + j) * 512]);
    }
    const float cs = csq_g[t * BTILE + ch * 32 + col];   // L2-resident, issued early

    // B fragments: lane-linear b128, zero conflicts.
    h8v bfr[2][4];
#pragma unroll
    for (int p = 0; p < 2; ++p)
#pragma unroll
      for (int kc4 = 0; kc4 < 4; ++kc4)
        bfr[p][kc4] = *(const h8v*)
            &ldsB[buf][(ch * 8 + p * 4 + kc4) * 512 + lane * 8];

    // 3 independent 4-deep chains: accA = h1g1; accB1 = h1g2'; accB2 = h2'g1.
    f16v accA  = {0.f,0.f,0.f,0.f,0.f,0.f,0.f,0.f,0.f,0.f,0.f,0.f,0.f,0.f,0.f,0.f};
    f16v accB1 = {0.f,0.f,0.f,0.f,0.f,0.f,0.f,0.f,0.f,0.f,0.f,0.f,0.f,0.f,0.f,0.f};
    f16v accB2 = {0.f,0.f,0.f,0.f,0.f,0.f,0.f,0.f,0.f,0.f,0.f,0.f,0.f,0.f,0.f,0.f};
#pragma unroll
    for (int kc4 = 0; kc4 < 4; ++kc4) {
      accA  = __builtin_amdgcn_mfma_f32_32x32x16_f16(afr[0][kc4], bfr[0][kc4], accA,  0, 0, 0);
      accB1 = __builtin_amdgcn_mfma_f32_32x32x16_f16(afr[0][kc4], bfr[1][kc4], accB1, 0, 0, 0);
      accB2 = __builtin_amdgcn_mfma_f32_32x32x16_f16(afr[1][kc4], bfr[0][kc4], accB2, 0, 0, 0);
    }

    const unsigned code = (unsigned)(t * BTILE + ch * 32 + col);
#pragma unroll
    for (int i = 0; i < 16; ++i) {
      const float acc = fmaf(accB1[i] + accB2[i], 2.44140625e-4f, accA[i]); // +2^-12 fold
      const float dist = fmaf(-2.f, acc, xq[i]) + cs;
      if (dist < bestD[i]) { bestD[i] = dist; bestC[i] = code; }  // first k wins
    }
    __syncthreads();   // waves done reading buf; prefetch into buf^1 drained
  }

  // ---- Reduce across the 32 col-lanes of each half (u64 min keeps lowest
  // code on exact ties), then across code-halves via LDS.
  unsigned long long key[16];
#pragma unroll
  for (int i = 0; i < 16; ++i)
    key[i] = ((unsigned long long)__float_as_uint(bestD[i]) << 32) | bestC[i];
#pragma unroll
  for (int i = 0; i < 16; ++i) {
#pragma unroll
    for (int m = 1; m < 32; m <<= 1) {
      const unsigned long long o = __shfl_xor(key[i], m, 64);
      if (o < key[i]) key[i] = o;
    }
  }
  if (col == 0) {
#pragma unroll
    for (int i = 0; i < 16; ++i) {
      const int row = s * 32 + (i & 3) + 8 * (i >> 2) + 4 * half;
      ldsRed[row][ch] = key[i];
    }
  }
  __syncthreads();
  if (tid < BROWS) {
    const unsigned long long a = ldsRed[tid][0];
    const unsigned long long b = ldsRed[tid][1];
    out[blockRow + tid] = (int)(unsigned)((a < b ? a : b) & 0xFFFFFFFFull);
  }
}

extern "C" void kernel_launch(void* const* d_in, const int* in_sizes, int n_in,
                              void* d_out, int out_size, void* d_ws, size_t ws_size,
                              hipStream_t stream) {
  const float* x  = (const float*)d_in[0];   // [N, 64] fp32
  const float* cb = (const float*)d_in[1];   // [K, 64] fp32
  int* out = (int*)d_out;                    // [N] int32

  // ws: bSwz (2 MB frag-ordered f16 planes) | csq (32 KB) | xsq (128 KB)
  _Float16* bSwz = (_Float16*)d_ws;
  float* csq_g = (float*)((char*)d_ws + (size_t)KC * DD * 2 * 2);
  float* xsq_g = csq_g + KC;

  vq_pre_kernel<<<dim3(KC / TPB + NROWS / TPB), dim3(TPB), 0, stream>>>(
      x, cb, bSwz, csq_g, xsq_g);
  vq_mfma_kernel<<<dim3(NROWS / BROWS), dim3(TPB), 0, stream>>>(
      x, bSwz, csq_g, xsq_g, out);
}

// Round 2
// 178.509 us; speedup vs baseline: 1.4761x; 1.0791x over previous
//
#include <hip/hip_runtime.h>
#include <math.h>

// VectorQuantizer: argmin_k ||x_n - c_k||^2, N=32768, K=8192, D=64, fp32.
// Round-8: counted-vmcnt 3-buffer pipeline + epilogue pipelined 1 tile back.
//
// Round-7 counters: 145.7us, MfmaUtil 30%, VALUBusy 44% -> per-tile lockstep:
// all 8 waves/CU did ds_read -> MFMA -> epilogue -> syncthreads in phase, so
// matrix and VALU pipes alternated idling. This round:
//  * T3/T4: barriers are "s_waitcnt vmcnt(5) lgkmcnt(0); s_barrier" (one asm).
//    Tile t+2's 5 loads (4x16B B-chunks + 1x4B csq slice, all global_load_lds)
//    stay in flight across 2 barriers; vmcnt never drains to 0 in the loop.
//    No VGPR-returning VMEM in the loop => compiler inserts no vmcnt waits.
//  * T15: argmin epilogue for tile t-1 runs inside body t (static 2-phase acc
//    sets, rule #20), co-issuing VALU into the MFMA pipe shadow; a wave never
//    waits on its own MFMA results before the barrier.
//  * accB1+accB2 merged into one 8-deep chained MFMA accumulator (m119:
//    C-chaining runs at peak) -- saves 16 fp32 adds + 16 VGPRs per phase.
//  * xsq computed in main prologue (quad shfl_xor reduce); pre-kernel is now
//    codebook-split only (32 blocks).
// Numerics identical in kind to round-7 (passed, absmax 0): 2-plane f16 split
// (plane1 denormal-zeroed, plane2 pre-scaled 2^12), 3 products, dist =
// fmaf(-2, fmaf(accB,2^-12,accA), xsq) + csq, strict < ascending code,
// u64 (distbits<<32|code) mins for cross-lane ties = first-occurrence.
// C/D layout (measured m74/m101): col=lane&31, row=(reg&3)+8*(reg>>2)+4*(lane>>5).

typedef __attribute__((ext_vector_type(8)))  _Float16 h8v;
typedef __attribute__((ext_vector_type(16))) float f16v;
typedef __attribute__((ext_vector_type(4)))  float f4v;

constexpr int NROWS = 32768;
constexpr int KC    = 8192;
constexpr int DD    = 64;
constexpr int TPB   = 256;                 // 4 waves
constexpr int BROWS = 64;                  // rows per block (2 stripes x 32)
constexpr int BTILE = 64;                  // codes per tile (2 x 32-code subtiles)
constexpr int NT    = KC / BTILE;          // 128 tiles
constexpr int TILE_HALFS = BTILE * DD * 2; // 8192 halves = 16 KB per tile in bSwz
constexpr int BUF_HALFS  = TILE_HALFS + 512; // + 4 wave-private csq slots (1 KB)

__device__ __forceinline__ void split2h(float v, _Float16& h1, _Float16& h2) {
  const float av = fabsf(v);
  _Float16 a = (_Float16)v;                  // RNE
  if (av < 6.1035156e-5f) a = (_Float16)0.f; // keep plane-1 out of f16 denormals
  h1 = a;
  h2 = (_Float16)((v - (float)a) * 4096.f);  // exact residual, scaled 2^12
}

__device__ __forceinline__ void gload_lds16(const void* g, void* l) {
  __builtin_amdgcn_global_load_lds(
      (const __attribute__((address_space(1))) void*)g,
      (__attribute__((address_space(3))) void*)l, 16, 0, 0);
}
__device__ __forceinline__ void gload_lds4(const void* g, void* l) {
  __builtin_amdgcn_global_load_lds(
      (const __attribute__((address_space(1))) void*)g,
      (__attribute__((address_space(3))) void*)l, 4, 0, 0);
}

// Pre-kernel (32 blocks): split cb -> frag-ordered bSwz (2 f16 planes) + csq.
__global__ void vq_pre_kernel(const float* __restrict__ cb,
                              _Float16* __restrict__ bSwz,
                              float* __restrict__ csq) {
  const int bid = blockIdx.x, tid = threadIdx.x;
  const int code = bid * TPB + tid;
  const float* cp = cb + (size_t)code * DD;
  float v[DD];
#pragma unroll
  for (int d = 0; d < DD; d += 4) {
    const float4 g = *(const float4*)(cp + d);
    v[d] = g.x; v[d + 1] = g.y; v[d + 2] = g.z; v[d + 3] = g.w;
  }
  float s = 0.f;
#pragma unroll
  for (int d = 0; d < DD; ++d) s = fmaf(v[d], v[d], s);
  csq[code] = s;
  _Float16 p1[DD], p2[DD];
#pragma unroll
  for (int d = 0; d < DD; ++d) split2h(v[d], p1[d], p2[d]);
  // 32-code group g, lane slot l; chunk (p,kc) holds 64 lanes x 8 f16:
  // lane (h*32+l) = code (g*32+l), k = kc*16 + h*8 + j.
  const int g = code >> 5, l = code & 31;
  _Float16* base = bSwz + (size_t)g * 4096;
#pragma unroll
  for (int p = 0; p < 2; ++p) {
    const _Float16* pl = p ? p2 : p1;
#pragma unroll
    for (int kc4 = 0; kc4 < 4; ++kc4)
#pragma unroll
      for (int h = 0; h < 2; ++h) {
        h8v wv;
#pragma unroll
        for (int j = 0; j < 8; ++j) wv[j] = pl[kc4 * 16 + h * 8 + j];
        *(h8v*)(base + (p * 4 + kc4) * 512 + (h * 32 + l) * 8) = wv;
      }
  }
}

// Body T: read tile T from buf BUFC, prefetch tile T+2 into buf PFB (5 async
// loads), issue 12 MFMAs for tile T, run epilogue for tile T-1 (prev-phase
// accs), then counted-vmcnt barrier. WN/DOEPI/DOISSUE are compile-time.
#define TILE_BODY(T, BUFC, PFB, AA, AB, CS, CODE, PA, PB, PCS, PCODE, DOEPI, DOISSUE, WN) \
  {                                                                                       \
    _Float16* bp = ldsBf + (BUFC) * BUF_HALFS;                                            \
    h8v b0[4], b1[4];                                                                     \
    {                                                                                     \
      const _Float16* rb = bp + (ch * 8) * 512 + lane * 8;                                \
      _Pragma("unroll")                                                                   \
      for (int kc = 0; kc < 4; ++kc) {                                                    \
        b0[kc] = *(const h8v*)(rb + kc * 512);                                            \
        b1[kc] = *(const h8v*)(rb + (4 + kc) * 512);                                      \
      }                                                                                   \
    }                                                                                     \
    CS = ((const float*)(bp + TILE_HALFS))[w * 64 + wcode];                               \
    CODE = (unsigned)((T) * 64) + wcode;                                                  \
    if (DOISSUE) {                                                                        \
      const _Float16* gs = bSwz + (size_t)((T) + 2) * TILE_HALFS + (w * 4) * 512 + lane * 8; \
      _Float16* ld = ldsBf + (PFB) * BUF_HALFS;                                           \
      _Pragma("unroll")                                                                   \
      for (int j = 0; j < 4; ++j)                                                         \
        gload_lds16(gs + j * 512, ld + (w * 4 + j) * 512);                                \
      gload_lds4(csq_g + ((T) + 2) * 64 + lane, (float*)(ld + TILE_HALFS) + w * 64);      \
    }                                                                                     \
    AA = __builtin_amdgcn_mfma_f32_32x32x16_f16(afr[0][0], b0[0], Zacc, 0, 0, 0);         \
    AB = __builtin_amdgcn_mfma_f32_32x32x16_f16(afr[0][0], b1[0], Zacc, 0, 0, 0);         \
    _Pragma("unroll")                                                                     \
    for (int kc = 1; kc < 4; ++kc) {                                                      \
      AA = __builtin_amdgcn_mfma_f32_32x32x16_f16(afr[0][kc], b0[kc], AA, 0, 0, 0);       \
      AB = __builtin_amdgcn_mfma_f32_32x32x16_f16(afr[0][kc], b1[kc], AB, 0, 0, 0);       \
    }                                                                                     \
    _Pragma("unroll")                                                                     \
    for (int kc = 0; kc < 4; ++kc)                                                        \
      AB = __builtin_amdgcn_mfma_f32_32x32x16_f16(afr[1][kc], b0[kc], AB, 0, 0, 0);       \
    if (DOEPI) {                                                                          \
      _Pragma("unroll")                                                                   \
      for (int i = 0; i < 16; ++i) {                                                      \
        const float a_ = fmaf(PB[i], 2.44140625e-4f, PA[i]);                              \
        const float d_ = fmaf(-2.f, a_, xq[i]) + PCS;                                     \
        if (d_ < bestD[i]) { bestD[i] = d_; bestC[i] = PCODE; }                           \
      }                                                                                   \
    }                                                                                     \
    asm volatile("s_waitcnt vmcnt(" #WN ") lgkmcnt(0)\n\ts_barrier" ::: "memory");        \
  }

__global__ __launch_bounds__(TPB, 2)
void vq_mfma_kernel(const float* __restrict__ x, const _Float16* __restrict__ bSwz,
                    const float* __restrict__ csq_g, int* __restrict__ out) {
  __shared__ alignas(16) _Float16 ldsA[2][BROWS][DD];     // 16384 B
  __shared__ alignas(16) _Float16 ldsBf[3 * BUF_HALFS];   // 52224 B
  __shared__ alignas(16) float ldsXsq[BROWS];             // 256 B
  __shared__ unsigned long long ldsRed[BROWS][2];         // 1024 B

  const int tid  = threadIdx.x;
  const int lane = tid & 63;
  const int w    = tid >> 6;
  const int s    = w & 1;        // row stripe (32 rows)
  const int ch   = w >> 1;       // code half (32 codes)
  const int half = lane >> 5;
  const int col  = lane & 31;
  const int wcode = ch * 32 + col;
  const int blockRow = blockIdx.x * BROWS;

  // ---- Issue tiles 0 and 1 (async DMA overlaps the A-split VALU below).
#pragma unroll
  for (int tt = 0; tt < 2; ++tt) {
    const _Float16* gs = bSwz + (size_t)tt * TILE_HALFS + (w * 4) * 512 + lane * 8;
    _Float16* ld = ldsBf + tt * BUF_HALFS;
#pragma unroll
    for (int j = 0; j < 4; ++j)
      gload_lds16(gs + j * 512, ld + (w * 4 + j) * 512);
    gload_lds4(csq_g + tt * 64 + lane, (float*)(ld + TILE_HALFS) + w * 64);
  }
  // ---- Stage A: split x rows into 2 f16 planes in LDS + xsq via quad reduce.
  {
    const int row = tid >> 2, dseg = (tid & 3) * 16;
    const float* xp = x + (size_t)(blockRow + row) * DD + dseg;
    float v[16];
#pragma unroll
    for (int d = 0; d < 16; d += 4) {
      const float4 g = *(const float4*)(xp + d);
      v[d] = g.x; v[d + 1] = g.y; v[d + 2] = g.z; v[d + 3] = g.w;
    }
    float p = 0.f;
#pragma unroll
    for (int e = 0; e < 16; ++e) p = fmaf(v[e], v[e], p);
    p += __shfl_xor(p, 1, 64);
    p += __shfl_xor(p, 2, 64);
    if ((tid & 3) == 0) ldsXsq[row] = p;     // per-row const; ~1-ulp reorder ok
    _Float16 qa[16], qb[16];
#pragma unroll
    for (int e = 0; e < 16; ++e) split2h(v[e], qa[e], qb[e]);
#pragma unroll
    for (int h2 = 0; h2 < 2; ++h2) {
      h8v a, b;
#pragma unroll
      for (int j = 0; j < 8; ++j) { a[j] = qa[h2 * 8 + j]; b[j] = qb[h2 * 8 + j]; }
      *(h8v*)&ldsA[0][row][dseg + h2 * 8] = a;
      *(h8v*)&ldsA[1][row][dseg + h2 * 8] = b;
    }
  }
  __syncthreads();   // full drain: tiles 0,1 + A planes + xsq resident

  // ---- A fragments resident: 2 planes x 4 kchunks x 8 f16 = 32 VGPR.
  h8v afr[2][4];
#pragma unroll
  for (int p = 0; p < 2; ++p)
#pragma unroll
    for (int kc4 = 0; kc4 < 4; ++kc4)
      afr[p][kc4] = *(const h8v*)&ldsA[p][s * 32 + col][kc4 * 16 + half * 8];

  // xsq for this lane's 16 C-slots: row = s*32 + (i&3) + 8*(i>>2) + 4*half.
  float xq[16];
  {
    const float* xb = &ldsXsq[s * 32 + 4 * half];
#pragma unroll
    for (int g8 = 0; g8 < 4; ++g8) {
      const f4v t4 = *(const f4v*)(xb + g8 * 8);
      xq[g8 * 4] = t4[0]; xq[g8 * 4 + 1] = t4[1];
      xq[g8 * 4 + 2] = t4[2]; xq[g8 * 4 + 3] = t4[3];
    }
  }

  float bestD[16];
  unsigned bestC[16];
#pragma unroll
  for (int i = 0; i < 16; ++i) { bestD[i] = INFINITY; bestC[i] = 0u; }

  const f16v Zacc = {0.f,0.f,0.f,0.f,0.f,0.f,0.f,0.f,0.f,0.f,0.f,0.f,0.f,0.f,0.f,0.f};
  f16v aA0 = Zacc, aB0 = Zacc, aA1 = Zacc, aB1 = Zacc;
  float cs0 = 0.f, cs1 = 0.f;
  unsigned code0 = 0u, code1 = 0u;

  // Tile T reads buf T%3; prefetch target (T+2)%3. Phase alternates 0/1 so
  // accs of tile T-1 survive into body T's epilogue (static indexing, #20).
  TILE_BODY(0, 0, 2, aA0, aB0, cs0, code0, aA1, aB1, cs1, code1, false, true, 5);
  TILE_BODY(1, 1, 0, aA1, aB1, cs1, code1, aA0, aB0, cs0, code0, true,  true, 5);
  for (int t = 2; t < 122; t += 6) {   // tiles 2..121, buf pattern 2,0,1,2,0,1
    TILE_BODY(t,     2, 1, aA0, aB0, cs0, code0, aA1, aB1, cs1, code1, true, true, 5);
    TILE_BODY(t + 1, 0, 2, aA1, aB1, cs1, code1, aA0, aB0, cs0, code0, true, true, 5);
    TILE_BODY(t + 2, 1, 0, aA0, aB0, cs0, code0, aA1, aB1, cs1, code1, true, true, 5);
    TILE_BODY(t + 3, 2, 1, aA1, aB1, cs1, code1, aA0, aB0, cs0, code0, true, true, 5);
    TILE_BODY(t + 4, 0, 2, aA0, aB0, cs0, code0, aA1, aB1, cs1, code1, true, true, 5);
    TILE_BODY(t + 5, 1, 0, aA1, aB1, cs1, code1, aA0, aB0, cs0, code0, true, true, 5);
  }
  TILE_BODY(122, 2, 1, aA0, aB0, cs0, code0, aA1, aB1, cs1, code1, true, true,  5);
  TILE_BODY(123, 0, 2, aA1, aB1, cs1, code1, aA0, aB0, cs0, code0, true, true,  5);
  TILE_BODY(124, 1, 0, aA0, aB0, cs0, code0, aA1, aB1, cs1, code1, true, true,  5);
  TILE_BODY(125, 2, 1, aA1, aB1, cs1, code1, aA0, aB0, cs0, code0, true, true,  5);
  TILE_BODY(126, 0, 2, aA0, aB0, cs0, code0, aA1, aB1, cs1, code1, true, false, 0);
  TILE_BODY(127, 1, 0, aA1, aB1, cs1, code1, aA0, aB0, cs0, code0, true, false, 0);
  // Final epilogue: tile 127 (phase-1 accs).
#pragma unroll
  for (int i = 0; i < 16; ++i) {
    const float a_ = fmaf(aB1[i], 2.44140625e-4f, aA1[i]);
    const float d_ = fmaf(-2.f, a_, xq[i]) + cs1;
    if (d_ < bestD[i]) { bestD[i] = d_; bestC[i] = code1; }
  }

  // ---- Reduce across the 32 col-lanes of each half (u64 min keeps lowest
  // code on exact ties), then across code-halves via LDS.
  unsigned long long key[16];
#pragma unroll
  for (int i = 0; i < 16; ++i)
    key[i] = ((unsigned long long)__float_as_uint(bestD[i]) << 32) | bestC[i];
#pragma unroll
  for (int i = 0; i < 16; ++i) {
#pragma unroll
    for (int m = 1; m < 32; m <<= 1) {
      const unsigned long long o = __shfl_xor(key[i], m, 64);
      if (o < key[i]) key[i] = o;
    }
  }
  if (col == 0) {
#pragma unroll
    for (int i = 0; i < 16; ++i) {
      const int row = s * 32 + (i & 3) + 8 * (i >> 2) + 4 * half;
      ldsRed[row][ch] = key[i];
    }
  }
  __syncthreads();
  if (tid < BROWS) {
    const unsigned long long a = ldsRed[tid][0];
    const unsigned long long b = ldsRed[tid][1];
    out[blockRow + tid] = (int)(unsigned)((a < b ? a : b) & 0xFFFFFFFFull);
  }
}

extern "C" void kernel_launch(void* const* d_in, const int* in_sizes, int n_in,
                              void* d_out, int out_size, void* d_ws, size_t ws_size,
                              hipStream_t stream) {
  const float* x  = (const float*)d_in[0];   // [N, 64] fp32
  const float* cb = (const float*)d_in[1];   // [K, 64] fp32
  int* out = (int*)d_out;                    // [N] int32

  // ws: bSwz (2 MB frag-ordered f16 planes) | csq (32 KB)
  _Float16* bSwz = (_Float16*)d_ws;
  float* csq_g = (float*)((char*)d_ws + (size_t)KC * DD * 2 * 2);

  vq_pre_kernel<<<dim3(KC / TPB), dim3(TPB), 0, stream>>>(cb, bSwz, csq_g);
  vq_mfma_kernel<<<dim3(NROWS / BROWS), dim3(TPB), 0, stream>>>(
      x, bSwz, csq_g, out);
}

// Round 3
// 176.755 us; speedup vs baseline: 1.4907x; 1.0099x over previous
//
#include <hip/hip_runtime.h>
#include <math.h>

// VectorQuantizer: argmin_k ||x_n - c_k||^2, N=32768, K=8192, D=64, fp32.
// Round-9: 2-stripe waves (64 rows/wave) -> B-LDS traffic per MFMA halves;
// all-epilogues-one-tile-late (full acc parity) -> wave never stalls on its
// own MFMA chain; 1 block/CU, 4 waves, VGPR-rich (launch_bounds(256,1)).
//
// Round-8 post-mortem: per CU per tile, 64x ds_read_b128 (770cy) ~= MFMA
// (775cy) -> LDS co-critical, MfmaUtil stuck at 39%. Here each wave computes
// 64 rows x 32 codes from the same 8KB B read (24 MFMAs), so per-CU LDS
// reads halve (385cy) and MFMA is the sole dominant pipe (2x margin).
//  * Counted-vmcnt 3-buffer pipeline unchanged from round-8 (proven):
//    5 global_load_lds per wave per tile, "s_waitcnt vmcnt(5) lgkmcnt(0);
//    s_barrier", never drains in-loop, per-wave drain covers cross-wave
//    chunk visibility at the barrier.
//  * All 4 accumulator pairs parity-double-buffered: body T runs epilogues
//    for tile T-1 only (static reg names, rule #20) -> zero same-tile acc
//    dependency; epilogue VALU issues in the 32cy gaps of paced MFMA issue.
//  * ldsA XOR-swizzle (slot ^= row&7) kills the 32-way prologue bank
//    conflict on afr reads (was the entire 524288-conflict counter).
//  * pre-kernel 4 threads/code (128 blocks).
// Numerics identical in kind to round-8 (passed, absmax 0): 2-plane f16
// split (plane1 denormal-zeroed, plane2 pre-scaled 2^12), 3 products via
// accA=h1g1 (4-chain) and accB=h1g2'+h2'g1 (8-chain), dist =
// fmaf(-2, fmaf(accB,2^-12,accA), xsq) + csq, strict < ascending code,
// u64 (distbits<<32|code) mins for cross-lane ties = first-occurrence.
// csq/xsq partial-sum order: 4-lane trees (same ~1-ulp class as round-8's
// xsq reorder, which passed).
// C/D layout (measured m74/m101): col=lane&31, row=(reg&3)+8*(reg>>2)+4*(lane>>5).

typedef __attribute__((ext_vector_type(8)))  _Float16 h8v;
typedef __attribute__((ext_vector_type(16))) float f16v;
typedef __attribute__((ext_vector_type(4)))  float f4v;

constexpr int NROWS = 32768;
constexpr int KC    = 8192;
constexpr int DD    = 64;
constexpr int TPB   = 256;                 // 4 waves
constexpr int BROWS = 128;                 // rows per block (4 stripes x 32)
constexpr int BTILE = 64;                  // codes per tile
constexpr int NT    = KC / BTILE;          // 128 tiles
constexpr int TILE_HALFS = BTILE * DD * 2; // 8192 halves = 16 KB per tile
constexpr int BUF_HALFS  = TILE_HALFS + 512; // + 4 wave-private csq slots (1 KB)

__device__ __forceinline__ void split2h(float v, _Float16& h1, _Float16& h2) {
  const float av = fabsf(v);
  _Float16 a = (_Float16)v;                  // RNE
  if (av < 6.1035156e-5f) a = (_Float16)0.f; // keep plane-1 out of f16 denormals
  h1 = a;
  h2 = (_Float16)((v - (float)a) * 4096.f);  // exact residual, scaled 2^12
}

__device__ __forceinline__ void gload_lds16(const void* g, void* l) {
  __builtin_amdgcn_global_load_lds(
      (const __attribute__((address_space(1))) void*)g,
      (__attribute__((address_space(3))) void*)l, 16, 0, 0);
}
__device__ __forceinline__ void gload_lds4(const void* g, void* l) {
  __builtin_amdgcn_global_load_lds(
      (const __attribute__((address_space(1))) void*)g,
      (__attribute__((address_space(3))) void*)l, 4, 0, 0);
}

// Pre-kernel (128 blocks, 4 threads/code): split cb -> frag-ordered bSwz
// (2 f16 planes) + csq (16-el fmaf chains + 4-lane shfl tree).
__global__ void vq_pre_kernel(const float* __restrict__ cb,
                              _Float16* __restrict__ bSwz,
                              float* __restrict__ csq) {
  const int gidx = blockIdx.x * TPB + threadIdx.x;  // 0..32767
  const int code = gidx >> 2;
  const int kc4  = gidx & 3;                        // this thread's k-chunk
  const float* cp = cb + (size_t)code * DD + kc4 * 16;
  float v[16];
#pragma unroll
  for (int d = 0; d < 16; d += 4) {
    const float4 g = *(const float4*)(cp + d);
    v[d] = g.x; v[d + 1] = g.y; v[d + 2] = g.z; v[d + 3] = g.w;
  }
  float s = 0.f;
#pragma unroll
  for (int d = 0; d < 16; ++d) s = fmaf(v[d], v[d], s);
  s += __shfl_xor(s, 1, 64);
  s += __shfl_xor(s, 2, 64);
  if (kc4 == 0) csq[code] = s;
  _Float16 p1[16], p2[16];
#pragma unroll
  for (int d = 0; d < 16; ++d) split2h(v[d], p1[d], p2[d]);
  // 32-code group g, lane slot l; chunk (p,kc) holds 64 lanes x 8 f16:
  // lane (h*32+l) = code (g*32+l), k = kc*16 + h*8 + j.
  const int g = code >> 5, l = code & 31;
  _Float16* base = bSwz + (size_t)g * 4096;
#pragma unroll
  for (int p = 0; p < 2; ++p) {
    const _Float16* pl = p ? p2 : p1;
#pragma unroll
    for (int h = 0; h < 2; ++h) {
      h8v wv;
#pragma unroll
      for (int j = 0; j < 8; ++j) wv[j] = pl[h * 8 + j];
      *(h8v*)(base + (p * 4 + kc4) * 512 + (h * 32 + l) * 8) = wv;
    }
  }
}

// Body T: read tile T from buf BUFC, prefetch tile T+2 into buf PFB, issue
// 24 MFMAs for tile T into cur-parity accs, run BOTH stripe epilogues for
// tile T-1 (prev-parity accs -> long-completed, zero stall), counted barrier.
#define TILE_BODY(T, BUFC, PFB, A0C, B0C, A1C, B1C, A0P, B0P, A1P, B1P, DOEPI, DOISSUE, WN) \
  {                                                                                   \
    const _Float16* bp = ldsBf + (BUFC) * BUF_HALFS;                                  \
    h8v b0[4], b1[4];                                                                 \
    {                                                                                 \
      const _Float16* rb = bp + (ch * 8) * 512 + lane * 8;                            \
      _Pragma("unroll")                                                               \
      for (int kc = 0; kc < 4; ++kc) {                                                \
        b0[kc] = *(const h8v*)(rb + kc * 512);                                        \
        b1[kc] = *(const h8v*)(rb + (4 + kc) * 512);                                  \
      }                                                                               \
    }                                                                                 \
    const float csC = ((const float*)(bp + TILE_HALFS))[w * 64 + wcode];              \
    if (DOISSUE) {                                                                    \
      const _Float16* gs = bSwz + (size_t)((T) + 2) * TILE_HALFS + (w * 4) * 512 + lane * 8; \
      _Float16* ld = ldsBf + (PFB) * BUF_HALFS;                                       \
      _Pragma("unroll")                                                               \
      for (int j = 0; j < 4; ++j)                                                     \
        gload_lds16(gs + j * 512, ld + (w * 4 + j) * 512);                            \
      gload_lds4(csq_g + ((T) + 2) * 64 + lane, (float*)(ld + TILE_HALFS) + w * 64);  \
    }                                                                                 \
    A0C = __builtin_amdgcn_mfma_f32_32x32x16_f16(afr[0][0][0], b0[0], Zacc, 0, 0, 0); \
    A1C = __builtin_amdgcn_mfma_f32_32x32x16_f16(afr[1][0][0], b0[0], Zacc, 0, 0, 0); \
    B0C = __builtin_amdgcn_mfma_f32_32x32x16_f16(afr[0][0][0], b1[0], Zacc, 0, 0, 0); \
    B1C = __builtin_amdgcn_mfma_f32_32x32x16_f16(afr[1][0][0], b1[0], Zacc, 0, 0, 0); \
    _Pragma("unroll")                                                                 \
    for (int kc = 1; kc < 4; ++kc) {                                                  \
      A0C = __builtin_amdgcn_mfma_f32_32x32x16_f16(afr[0][0][kc], b0[kc], A0C, 0, 0, 0); \
      A1C = __builtin_amdgcn_mfma_f32_32x32x16_f16(afr[1][0][kc], b0[kc], A1C, 0, 0, 0); \
      B0C = __builtin_amdgcn_mfma_f32_32x32x16_f16(afr[0][0][kc], b1[kc], B0C, 0, 0, 0); \
      B1C = __builtin_amdgcn_mfma_f32_32x32x16_f16(afr[1][0][kc], b1[kc], B1C, 0, 0, 0); \
    }                                                                                 \
    if (DOEPI) {                                                                      \
      const unsigned pcode = (unsigned)(((T) - 1) * 64) + wcode;                      \
      _Pragma("unroll")                                                               \
      for (int i = 0; i < 16; ++i) {                                                  \
        const float a_ = fmaf(B0P[i], 2.44140625e-4f, A0P[i]);                        \
        const float d_ = fmaf(-2.f, a_, xq[i]) + csP;                                 \
        if (d_ < bestD[i]) { bestD[i] = d_; bestC[i] = pcode; }                       \
      }                                                                               \
    }                                                                                 \
    _Pragma("unroll")                                                                 \
    for (int kc = 0; kc < 4; ++kc) {                                                  \
      B0C = __builtin_amdgcn_mfma_f32_32x32x16_f16(afr[0][1][kc], b0[kc], B0C, 0, 0, 0); \
      B1C = __builtin_amdgcn_mfma_f32_32x32x16_f16(afr[1][1][kc], b0[kc], B1C, 0, 0, 0); \
    }                                                                                 \
    if (DOEPI) {                                                                      \
      const unsigned pcode = (unsigned)(((T) - 1) * 64) + wcode;                      \
      _Pragma("unroll")                                                               \
      for (int i = 0; i < 16; ++i) {                                                  \
        const float a_ = fmaf(B1P[i], 2.44140625e-4f, A1P[i]);                        \
        const float d_ = fmaf(-2.f, a_, xq[16 + i]) + csP;                            \
        if (d_ < bestD[16 + i]) { bestD[16 + i] = d_; bestC[16 + i] = pcode; }        \
      }                                                                               \
    }                                                                                 \
    csP = csC;                                                                        \
    asm volatile("s_waitcnt vmcnt(" #WN ") lgkmcnt(0)\n\ts_barrier" ::: "memory");    \
  }

__global__ __launch_bounds__(TPB, 1)
void vq_mfma_kernel(const float* __restrict__ x, const _Float16* __restrict__ bSwz,
                    const float* __restrict__ csq_g, int* __restrict__ out) {
  __shared__ alignas(16) _Float16 ldsAf[2 * BROWS * 8 * 8];   // 32768 B, swizzled
  __shared__ alignas(16) _Float16 ldsBf[3 * BUF_HALFS];       // 52224 B
  __shared__ alignas(16) float ldsXsq[BROWS];                 // 512 B
  __shared__ alignas(16) unsigned long long ldsRed[BROWS][2]; // 2048 B

  const int tid  = threadIdx.x;
  const int lane = tid & 63;
  const int w    = tid >> 6;
  const int ch   = w & 1;        // code half (32 codes)
  const int rs   = w >> 1;       // row half (64 rows = 2 stripes)
  const int half = lane >> 5;
  const int col  = lane & 31;
  const int wcode = ch * 32 + col;
  const int blockRow = blockIdx.x * BROWS;

  // ---- Issue tiles 0 and 1 (async DMA overlaps the A-split VALU below).
#pragma unroll
  for (int tt = 0; tt < 2; ++tt) {
    const _Float16* gs = bSwz + (size_t)tt * TILE_HALFS + (w * 4) * 512 + lane * 8;
    _Float16* ld = ldsBf + tt * BUF_HALFS;
#pragma unroll
    for (int j = 0; j < 4; ++j)
      gload_lds16(gs + j * 512, ld + (w * 4 + j) * 512);
    gload_lds4(csq_g + tt * 64 + lane, (float*)(ld + TILE_HALFS) + w * 64);
  }
  // ---- Stage A: split 128 x-rows into 2 f16 planes (XOR-swizzled) + xsq.
  {
    const int row = tid >> 1, off32 = (tid & 1) * 32;
    const float* xp = x + (size_t)(blockRow + row) * DD + off32;
    float v[32];
#pragma unroll
    for (int d = 0; d < 32; d += 4) {
      const float4 g = *(const float4*)(xp + d);
      v[d] = g.x; v[d + 1] = g.y; v[d + 2] = g.z; v[d + 3] = g.w;
    }
    float p = 0.f;
#pragma unroll
    for (int e = 0; e < 32; ++e) p = fmaf(v[e], v[e], p);
    p += __shfl_xor(p, 1, 64);               // pair-tree; per-row const
    if ((tid & 1) == 0) ldsXsq[row] = p;
    _Float16 qa[32], qb[32];
#pragma unroll
    for (int e = 0; e < 32; ++e) split2h(v[e], qa[e], qb[e]);
#pragma unroll
    for (int pidx = 0; pidx < 2; ++pidx) {
      const _Float16* ql = pidx ? qb : qa;
#pragma unroll
      for (int h2 = 0; h2 < 4; ++h2) {
        h8v wv;
#pragma unroll
        for (int j = 0; j < 8; ++j) wv[j] = ql[h2 * 8 + j];
        const int slot = (tid & 1) * 4 + h2;         // 16B slot (d/8)
        *(h8v*)&ldsAf[((pidx * BROWS + row) * 8 + (slot ^ (row & 7))) * 8] = wv;
      }
    }
  }
  __syncthreads();   // full drain: tiles 0,1 + A planes + xsq resident

  // ---- A fragments resident: 2 stripes x 2 planes x 4 kchunks = 64 VGPR.
  h8v afr[2][2][4];
#pragma unroll
  for (int q = 0; q < 2; ++q)
#pragma unroll
    for (int p = 0; p < 2; ++p)
#pragma unroll
      for (int kc = 0; kc < 4; ++kc) {
        const int arow = rs * 64 + q * 32 + col;
        const int slot = kc * 2 + half;
        afr[q][p][kc] =
            *(const h8v*)&ldsAf[((p * BROWS + arow) * 8 + (slot ^ (arow & 7))) * 8];
      }

  // xsq for this lane's 32 C-slots: row = rs*64 + q*32 + (i&3)+8*(i>>2)+4*half.
  float xq[32];
#pragma unroll
  for (int q = 0; q < 2; ++q) {
    const float* xb = &ldsXsq[rs * 64 + q * 32 + 4 * half];
#pragma unroll
    for (int g8 = 0; g8 < 4; ++g8) {
      const f4v t4 = *(const f4v*)(xb + g8 * 8);
      xq[q * 16 + g8 * 4]     = t4[0]; xq[q * 16 + g8 * 4 + 1] = t4[1];
      xq[q * 16 + g8 * 4 + 2] = t4[2]; xq[q * 16 + g8 * 4 + 3] = t4[3];
    }
  }

  float bestD[32];
  unsigned bestC[32];
#pragma unroll
  for (int i = 0; i < 32; ++i) { bestD[i] = INFINITY; bestC[i] = 0u; }

  const f16v Zacc = {0.f,0.f,0.f,0.f,0.f,0.f,0.f,0.f,0.f,0.f,0.f,0.f,0.f,0.f,0.f,0.f};
  f16v aA0e = Zacc, aB0e = Zacc, aA1e = Zacc, aB1e = Zacc;   // even-tile accs
  f16v aA0o = Zacc, aB0o = Zacc, aA1o = Zacc, aB1o = Zacc;   // odd-tile accs
  float csP = 0.f;

  // Tile T reads buf T%3, prefetches into (T+2)%3; parity = T&1 selects the
  // cur acc set; epilogues always read the prev-parity set (tile T-1).
  TILE_BODY(0, 0, 2, aA0e, aB0e, aA1e, aB1e, aA0o, aB0o, aA1o, aB1o, false, true, 5);
  TILE_BODY(1, 1, 0, aA0o, aB0o, aA1o, aB1o, aA0e, aB0e, aA1e, aB1e, true,  true, 5);
  for (int t = 2; t < 122; t += 6) {   // tiles 2..121, buf pattern 2,0,1,2,0,1
    TILE_BODY(t,     2, 1, aA0e, aB0e, aA1e, aB1e, aA0o, aB0o, aA1o, aB1o, true, true, 5);
    TILE_BODY(t + 1, 0, 2, aA0o, aB0o, aA1o, aB1o, aA0e, aB0e, aA1e, aB1e, true, true, 5);
    TILE_BODY(t + 2, 1, 0, aA0e, aB0e, aA1e, aB1e, aA0o, aB0o, aA1o, aB1o, true, true, 5);
    TILE_BODY(t + 3, 2, 1, aA0o, aB0o, aA1o, aB1o, aA0e, aB0e, aA1e, aB1e, true, true, 5);
    TILE_BODY(t + 4, 0, 2, aA0e, aB0e, aA1e, aB1e, aA0o, aB0o, aA1o, aB1o, true, true, 5);
    TILE_BODY(t + 5, 1, 0, aA0o, aB0o, aA1o, aB1o, aA0e, aB0e, aA1e, aB1e, true, true, 5);
  }
  TILE_BODY(122, 2, 1, aA0e, aB0e, aA1e, aB1e, aA0o, aB0o, aA1o, aB1o, true, true,  5);
  TILE_BODY(123, 0, 2, aA0o, aB0o, aA1o, aB1o, aA0e, aB0e, aA1e, aB1e, true, true,  5);
  TILE_BODY(124, 1, 0, aA0e, aB0e, aA1e, aB1e, aA0o, aB0o, aA1o, aB1o, true, true,  5);
  TILE_BODY(125, 2, 1, aA0o, aB0o, aA1o, aB1o, aA0e, aB0e, aA1e, aB1e, true, true,  5);
  TILE_BODY(126, 0, 0, aA0e, aB0e, aA1e, aB1e, aA0o, aB0o, aA1o, aB1o, true, false, 0);
  TILE_BODY(127, 1, 0, aA0o, aB0o, aA1o, aB1o, aA0e, aB0e, aA1e, aB1e, true, false, 0);
  // Final epilogues: tile 127 (odd set), cs of 127 in csP.
  {
    const unsigned code127 = (unsigned)(127 * 64) + wcode;
#pragma unroll
    for (int i = 0; i < 16; ++i) {
      const float a_ = fmaf(aB0o[i], 2.44140625e-4f, aA0o[i]);
      const float d_ = fmaf(-2.f, a_, xq[i]) + csP;
      if (d_ < bestD[i]) { bestD[i] = d_; bestC[i] = code127; }
    }
#pragma unroll
    for (int i = 0; i < 16; ++i) {
      const float a_ = fmaf(aB1o[i], 2.44140625e-4f, aA1o[i]);
      const float d_ = fmaf(-2.f, a_, xq[16 + i]) + csP;
      if (d_ < bestD[16 + i]) { bestD[16 + i] = d_; bestC[16 + i] = code127; }
    }
  }

  // ---- Reduce across the 32 col-lanes of each half (u64 min keeps lowest
  // code on exact ties), then across code-halves via LDS.
  unsigned long long key[32];
#pragma unroll
  for (int i = 0; i < 32; ++i)
    key[i] = ((unsigned long long)__float_as_uint(bestD[i]) << 32) | bestC[i];
#pragma unroll
  for (int i = 0; i < 32; ++i) {
#pragma unroll
    for (int m = 1; m < 32; m <<= 1) {
      const unsigned long long o = __shfl_xor(key[i], m, 64);
      if (o < key[i]) key[i] = o;
    }
  }
  if (col == 0) {
#pragma unroll
    for (int i = 0; i < 32; ++i) {
      const int ii = i & 15, q = i >> 4;
      const int row = rs * 64 + q * 32 + (ii & 3) + 8 * (ii >> 2) + 4 * half;
      ldsRed[row][ch] = key[i];
    }
  }
  __syncthreads();
  if (tid < BROWS) {
    const unsigned long long a = ldsRed[tid][0];
    const unsigned long long b = ldsRed[tid][1];
    out[blockRow + tid] = (int)(unsigned)((a < b ? a : b) & 0xFFFFFFFFull);
  }
}

extern "C" void kernel_launch(void* const* d_in, const int* in_sizes, int n_in,
                              void* d_out, int out_size, void* d_ws, size_t ws_size,
                              hipStream_t stream) {
  const float* x  = (const float*)d_in[0];   // [N, 64] fp32
  const float* cb = (const float*)d_in[1];   // [K, 64] fp32
  int* out = (int*)d_out;                    // [N] int32

  // ws: bSwz (2 MB frag-ordered f16 planes) | csq (32 KB)
  _Float16* bSwz = (_Float16*)d_ws;
  float* csq_g = (float*)((char*)d_ws + (size_t)KC * DD * 2 * 2);

  vq_pre_kernel<<<dim3(KC * 4 / TPB), dim3(TPB), 0, stream>>>(cb, bSwz, csq_g);
  vq_mfma_kernel<<<dim3(NROWS / BROWS), dim3(TPB), 0, stream>>>(
      x, bSwz, csq_g, out);
}